// Round 1
// baseline (188.242 us; speedup 1.0000x reference)
//
#include <hip/hip_runtime.h>
#include <hip/hip_bf16.h>
#include <math.h>

#define T_TOKENS 16384
#define DDIM 2048
#define NEXP 64
#define TOKS_PER_WAVE 8
#define WAVES_PER_BLOCK 4
#define TOKS_PER_BLOCK (TOKS_PER_WAVE * WAVES_PER_BLOCK)   // 32
#define CHUNK_D 128
#define NCHUNK (DDIM / CHUNK_D)                            // 16
#define LDS_STRIDE 132                                     // 128 + 4 pad; rows stay 16B-aligned
#define REFINE_TAU 1e-3f

__device__ __forceinline__ bool better(double va, int ia, double vb, int ib) {
    return (va > vb) || (va == vb && ia < ib);
}

__global__ __launch_bounds__(256, 2)
void moe_router_kernel(const float* __restrict__ x,
                       const float* __restrict__ W,
                       float* __restrict__ out) {
    __shared__ float wlds[NEXP * LDS_STRIDE];

    const int tid  = threadIdx.x;
    const int lane = tid & 63;
    const int wave = __builtin_amdgcn_readfirstlane(tid >> 6);  // force SGPR -> uniform x addrs
    const int tok0 = blockIdx.x * TOKS_PER_BLOCK + wave * TOKS_PER_WAVE;

    float4 acc[TOKS_PER_WAVE];
#pragma unroll
    for (int t = 0; t < TOKS_PER_WAVE; ++t) acc[t] = make_float4(0.f, 0.f, 0.f, 0.f);

    // staging map: thread -> (row e, quad q): 2 contiguous 512B rows per wave -> coalesced
    const int se = tid >> 5;   // 0..7
    const int sq = tid & 31;   // 0..31

    const float* __restrict__ xbase = x + (size_t)tok0 * DDIM;

    for (int c = 0; c < NCHUNK; ++c) {
        const int d0 = c * CHUNK_D;

        // ---- stage W[0:64][d0:d0+128] -> LDS [64][132] ----
#pragma unroll
        for (int p = 0; p < 8; ++p) {
            const int e = se + p * 8;
            const float4 v = *reinterpret_cast<const float4*>(
                &W[(size_t)e * DDIM + d0 + sq * 4]);
            *reinterpret_cast<float4*>(&wlds[e * LDS_STRIDE + sq * 4]) = v;
        }
        __syncthreads();

        // ---- broadcast-FMA main loop ----
        const float4* __restrict__ wrow =
            reinterpret_cast<const float4*>(&wlds[lane * LDS_STRIDE]);
#pragma unroll 4
        for (int q = 0; q < CHUNK_D / 4; ++q) {
            const float4 wv = wrow[q];           // per-lane ds_read_b128
#pragma unroll
            for (int t = 0; t < TOKS_PER_WAVE; ++t) {
                // uniform address -> s_load (broadcast x over the 64 expert-lanes)
                const float4 xv = *reinterpret_cast<const float4*>(
                    &xbase[t * DDIM + d0 + q * 4]);
                acc[t].x = fmaf(xv.x, wv.x, acc[t].x);
                acc[t].y = fmaf(xv.y, wv.y, acc[t].y);
                acc[t].z = fmaf(xv.z, wv.z, acc[t].z);
                acc[t].w = fmaf(xv.w, wv.w, acc[t].w);
            }
        }
        __syncthreads();
    }

    // ---- epilogue: per token, lane e holds logit[e]; softmax + top-2 across lanes ----
    float* __restrict__ outw = out;                              // [T][2] weights
    float* __restrict__ outi = out + (size_t)T_TOKENS * 2;       // [T][2] indices (as float)

#pragma unroll 1
    for (int t = 0; t < TOKS_PER_WAVE; ++t) {
        const float l = (acc[t].x + acc[t].y) + (acc[t].z + acc[t].w);

        // top-1 (argmax, ties -> lower index, matches lax.top_k)
        float v1 = l; int i1 = lane;
#pragma unroll
        for (int off = 32; off >= 1; off >>= 1) {
            const float ov = __shfl_xor(v1, off);
            const int   oi = __shfl_xor(i1, off);
            if (ov > v1 || (ov == v1 && oi < i1)) { v1 = ov; i1 = oi; }
        }
        // top-2
        float v2 = (lane == i1) ? -INFINITY : l; int i2 = lane;
#pragma unroll
        for (int off = 32; off >= 1; off >>= 1) {
            const float ov = __shfl_xor(v2, off);
            const int   oi = __shfl_xor(i2, off);
            if (ov > v2 || (ov == v2 && oi < i2)) { v2 = ov; i2 = oi; }
        }
        // top-3 (candidate for refinement)
        float v3 = (lane == i1 || lane == i2) ? -INFINITY : l; int i3 = lane;
#pragma unroll
        for (int off = 32; off >= 1; off >>= 1) {
            const float ov = __shfl_xor(v3, off);
            const int   oi = __shfl_xor(i3, off);
            if (ov > v3 || (ov == v3 && oi < i3)) { v3 = ov; i3 = oi; }
        }

        // softmax pieces (order-invariant in the final ratio)
        const float p = expf(l - v1);
        float s = p;
#pragma unroll
        for (int off = 32; off >= 1; off >>= 1) s += __shfl_xor(s, off);

        int iA = i1, iB = i2;
        // near-tie -> recompute 3 candidate logits in f64 and re-rank (wave-uniform branch)
        if ((v1 - v2) < REFINE_TAU || (v2 - v3) < REFINE_TAU) {
            const float* __restrict__ xrow = x + (size_t)(tok0 + t) * DDIM;
            double L[3]; int I[3] = { i1, i2, i3 };
#pragma unroll 1
            for (int cnd = 0; cnd < 3; ++cnd) {
                const float* __restrict__ wr = W + (size_t)I[cnd] * DDIM;
                double sd = 0.0;
                for (int d = lane; d < DDIM; d += 64)
                    sd = fma((double)xrow[d], (double)wr[d], sd);
#pragma unroll
                for (int off = 32; off >= 1; off >>= 1) sd += __shfl_xor(sd, off);
                L[cnd] = sd;
            }
            // sort 3 candidates (desc value, ties -> lower index)
            if (!better(L[0], I[0], L[1], I[1])) { double tv = L[0]; L[0] = L[1]; L[1] = tv; int ti = I[0]; I[0] = I[1]; I[1] = ti; }
            if (!better(L[1], I[1], L[2], I[2])) { double tv = L[1]; L[1] = L[2]; L[2] = tv; int ti = I[1]; I[1] = I[2]; I[2] = ti; }
            if (!better(L[0], I[0], L[1], I[1])) { double tv = L[0]; L[0] = L[1]; L[1] = tv; int ti = I[0]; I[0] = I[1]; I[1] = ti; }
            iA = I[0]; iB = I[1];
        }

        const float pA = __shfl(p, iA);
        const float pB = __shfl(p, iB);
        const float pa = pA / s;
        const float pb = pB / s;
        const float inv = 1.0f / (pa + pb + 1e-9f);

        if (lane == 0) {
            const size_t tg = (size_t)(tok0 + t);
            outw[tg * 2]     = pa * inv;
            outw[tg * 2 + 1] = pb * inv;
            outi[tg * 2]     = (float)iA;
            outi[tg * 2 + 1] = (float)iB;
        }
    }
}

extern "C" void kernel_launch(void* const* d_in, const int* in_sizes, int n_in,
                              void* d_out, int out_size, void* d_ws, size_t ws_size,
                              hipStream_t stream) {
    const float* x = (const float*)d_in[0];
    const float* W = (const float*)d_in[1];
    float* out = (float*)d_out;
    const int grid = T_TOKENS / TOKS_PER_BLOCK;  // 512 blocks x 256 threads = 2048 waves
    moe_router_kernel<<<grid, 256, 0, stream>>>(x, W, out);
}